// Round 1
// baseline (4923.116 us; speedup 1.0000x reference)
//
#include <hip/hip_runtime.h>

#define NUMS   128
#define NVARS  16
#define BATCH  8192
#define ITERS  15

// d_out element offsets (return order: cv, cp, cr, acc_fixed, acc_primal, primal_stack, fixed_stack)
#define OUT_ACCF (3*BATCH*NVARS)           // 393216
#define OUT_ACCP (OUT_ACCF + BATCH)        // 401408
#define OUT_PST  (OUT_ACCP + BATCH)        // 409600
#define OUT_FST  (OUT_PST + ITERS*BATCH)   // 532480

// ---------------------------------------------------------------------------
// prep: AtA = 2(P^T P + Pd^T Pd + Pdd^T Pdd); cost_mat = [[I+AtA, Aeq^T],[Aeq,0]];
// M = inv(cost_mat) via f64 Gauss-Jordan. ws: [0,324) M row-major f32,
// [324,596) AtA padded [16][17] f32.
// ---------------------------------------------------------------------------
__global__ void prep_kernel(const float* __restrict__ P, const float* __restrict__ Pd,
                            const float* __restrict__ Pdd, float* __restrict__ ws)
{
    __shared__ double GA[18][36];
    __shared__ float  ata[16][16];
    __shared__ double piv_s;
    const int t = threadIdx.x;

    if (t < 256) {
        int j = t >> 4, k = t & 15;
        float s = 0.f;
        for (int i = 0; i < NUMS; ++i)
            s += P[i*16+j]*P[i*16+k] + Pd[i*16+j]*Pd[i*16+k] + Pdd[i*16+j]*Pdd[i*16+k];
        ata[j][k] = 2.f * s;
    }
    __syncthreads();

    const int gi = t / 36, gj = t % 36;   // t < 648 always (blockDim = 648)
    {
        double v;
        if (gj < 18) {
            if (gi < 16 && gj < 16)      v = (gi == gj ? 1.0 : 0.0) + (double)ata[gi][gj];
            else if (gi < 16)            v = (gj == 16) ? (double)P[gi] : (double)Pd[gi];
            else if (gj < 16)            v = (gi == 16) ? (double)P[gj] : (double)Pd[gj];
            else                         v = 0.0;
        } else {
            v = ((gj - 18) == gi) ? 1.0 : 0.0;
        }
        GA[gi][gj] = v;
    }
    __syncthreads();

    for (int k = 0; k < 18; ++k) {
        if (t == 0) piv_s = GA[k][k];
        __syncthreads();
        if (gi == k) GA[gi][gj] /= piv_s;
        __syncthreads();
        double f  = GA[gi][k];
        double rk = GA[k][gj];
        __syncthreads();
        if (gi != k) GA[gi][gj] -= f * rk;
        __syncthreads();
    }

    if (gj >= 18) ws[gi*18 + (gj - 18)] = (float)GA[gi][gj];
    if (t < 256)  ws[324 + (t >> 4)*17 + (t & 15)] = ata[t >> 4][t & 15];
    if (t >= 256 && t < 272) ws[324 + (t - 256)*17 + 16] = 0.f;
}

// ---------------------------------------------------------------------------
// main solver: block = 192 threads = 12 groups of 16 lanes = 4 rows x 3 channels
// ---------------------------------------------------------------------------
__device__ __forceinline__ void bfly16(float (&v)[16], float& a, float& b)
{
#pragma unroll
    for (int s = 1; s < 16; s <<= 1) {
#pragma unroll
        for (int j = 0; j < 16; ++j) v[j] += __shfl_xor(v[j], s, 16);
        a += __shfl_xor(a, s, 16);
        b += __shfl_xor(b, s, 16);
    }
}

__launch_bounds__(192, 2)
__global__ void solve_kernel(
    const float* __restrict__ P,    const float* __restrict__ Pd,   const float* __restrict__ Pdd,
    const float* __restrict__ lamv, const float* __restrict__ lamp, const float* __restrict__ lamr,
    const float* __restrict__ cinv, const float* __restrict__ cinp, const float* __restrict__ cinr,
    const float* __restrict__ beqv, const float* __restrict__ beqp, const float* __restrict__ beqr,
    const float* __restrict__ c0v,  const float* __restrict__ c0p,  const float* __restrict__ c0r,
    float* __restrict__ out, const float* __restrict__ ws)
{
    __shared__ __align__(16) float Pt[3][16][128];   // transposed: Pt[m][j][i]
    __shared__ float Ml[16][19];                     // M rows 0..15, cols 0..17 (pad 19)
    __shared__ float ata[16][17];
    __shared__ float res_st[ITERS][12];
    __shared__ float fix_st[ITERS][12];

    // ---- stage constants ----
#pragma unroll
    for (int m = 0; m < 3; ++m) {
        const float* src = (m == 0) ? P : (m == 1) ? Pd : Pdd;
        for (int f = threadIdx.x; f < 2048; f += 192) {
            int j = f >> 7, i = f & 127;
            Pt[m][j][i] = src[i*16 + j];
        }
    }
    for (int f = threadIdx.x; f < 288; f += 192) Ml[f / 18][f % 18] = ws[f];
    for (int f = threadIdx.x; f < 272; f += 192) ((float*)ata)[f] = ws[324 + f];
    __syncthreads();

    const int g  = threadIdx.x >> 4;   // group 0..11
    const int l  = threadIdx.x & 15;   // lane-in-group
    const int rl = g / 3;              // local row 0..3
    const int ch = g - rl * 3;         // channel 0..2
    const int row = blockIdx.x * 4 + rl;

    const float* lam_p = (ch == 0) ? lamv : (ch == 1) ? lamp : lamr;
    const float* cin_p = (ch == 0) ? cinv : (ch == 1) ? cinp : cinr;
    const float* beq_p = (ch == 0) ? beqv : (ch == 1) ? beqp : beqr;
    const float* c0_p  = (ch == 0) ? c0v  : (ch == 1) ? c0p  : c0r;

    // bounds per (ch, m): m=0 pos-limits, m=1 vel-limits, m=2 acc-limits of the channel
    float bmax[3], bmin[3];
    bmax[0] = (ch == 0) ? 20.f : (ch == 1) ? 0.2f  : 0.25f;
    bmin[0] = (ch == 0) ? 12.f : (ch == 1) ? -0.2f : -0.25f;
    bmax[1] = (ch == 0) ? 3.f  : 0.25f;
    bmin[1] = (ch == 0) ? -3.f : -0.25f;
    bmax[2] = (ch == 0) ? 3.f  : 0.15f;
    bmin[2] = (ch == 0) ? -3.f : -0.15f;

    // ---- per-unit state (replicated across the 16 lanes of the group) ----
    float c[16], L[16], cq[16], pj[16], uo[3][8];
    float beq0, beq1, c_dist = 0.f;
    {
        const float4* cp4 = (const float4*)(c0_p  + row * 16);
        const float4* lp4 = (const float4*)(lam_p + row * 16);
        const float4* ip4 = (const float4*)(cin_p + row * 16);
#pragma unroll
        for (int q = 0; q < 4; ++q) {
            float4 a = cp4[q];
            c[4*q+0] = a.x; c[4*q+1] = a.y; c[4*q+2] = a.z; c[4*q+3] = a.w;
            float4 b = lp4[q]; float4 d = ip4[q];
            L[4*q+0] = b.x + d.x; L[4*q+1] = b.y + d.y;
            L[4*q+2] = b.z + d.z; L[4*q+3] = b.w + d.w;
        }
        float2 e = *(const float2*)(beq_p + row * 2);
        beq0 = e.x; beq1 = e.y;
    }

    // ---- init pass: u0, rv0 -> proj0, cq0 = AtA*c0 ----
    {
        float pjp[16];
#pragma unroll
        for (int j = 0; j < 16; ++j) pjp[j] = 0.f;
#pragma unroll
        for (int m = 0; m < 3; ++m) {
            float un[8], h[8];
#pragma unroll
            for (int k = 0; k < 8; ++k) un[k] = 0.f;
#pragma unroll
            for (int j = 0; j < 16; ++j) {
                float4 p0 = *(const float4*)&Pt[m][j][4*l];
                float4 p1 = *(const float4*)&Pt[m][j][64 + 4*l];
                un[0] += c[j]*p0.x; un[1] += c[j]*p0.y; un[2] += c[j]*p0.z; un[3] += c[j]*p0.w;
                un[4] += c[j]*p1.x; un[5] += c[j]*p1.y; un[6] += c[j]*p1.z; un[7] += c[j]*p1.w;
            }
#pragma unroll
            for (int k = 0; k < 8; ++k) {
                float x = un[k] - bmax[m];
                float rvp = fmaxf(x, 0.f);
                float y = un[k] - bmin[m];
                float rvm = fmaxf(-y, 0.f);
                h[k] = rvp - rvm;
                uo[m][k] = un[k];
            }
#pragma unroll
            for (int j = 0; j < 16; ++j) {
                float4 p0 = *(const float4*)&Pt[m][j][4*l];
                float4 p1 = *(const float4*)&Pt[m][j][64 + 4*l];
                pjp[j] += h[0]*p0.x + h[1]*p0.y + h[2]*p0.z + h[3]*p0.w
                        + h[4]*p1.x + h[5]*p1.y + h[6]*p1.z + h[7]*p1.w;
            }
        }
        float d0 = 0.f, d1 = 0.f;
        bfly16(pjp, d0, d1);
#pragma unroll
        for (int j = 0; j < 16; ++j) pj[j] = pjp[j];
        float cqd = 0.f;
#pragma unroll
        for (int k = 0; k < 16; ++k) cqd += ata[l][k] * c[k];
#pragma unroll
        for (int k = 0; k < 16; ++k) cq[k] = __shfl(cqd, k, 16);
    }

    // ---- 15 ADMM iterations ----
    for (int t = 0; t < ITERS; ++t) {
        // rhs = [L + Q c_prev - proj_prev ; b_eq]; distributed solve: lane l owns M row l
        float sj = 0.f;
        {
            float r[16];
#pragma unroll
            for (int k = 0; k < 16; ++k) r[k] = L[k] + cq[k] - pj[k];
#pragma unroll
            for (int k = 0; k < 16; ++k) sj += Ml[l][k] * r[k];
            sj += Ml[l][16] * beq0 + Ml[l][17] * beq1;
        }
        c_dist = sj;
        float cdel2 = 0.f;
#pragma unroll
        for (int k = 0; k < 16; ++k) {
            float cn = __shfl(sj, k, 16);
            float d = cn - c[k];
            cdel2 += d * d;
            c[k] = cn;
        }

        float res2 = 0.f, ds2 = 0.f;
        float pjp[16];
#pragma unroll
        for (int j = 0; j < 16; ++j) pjp[j] = 0.f;

#pragma unroll
        for (int m = 0; m < 3; ++m) {
            float un[8], h[8];
#pragma unroll
            for (int k = 0; k < 8; ++k) un[k] = 0.f;
#pragma unroll
            for (int j = 0; j < 16; ++j) {
                float4 p0 = *(const float4*)&Pt[m][j][4*l];
                float4 p1 = *(const float4*)&Pt[m][j][64 + 4*l];
                un[0] += c[j]*p0.x; un[1] += c[j]*p0.y; un[2] += c[j]*p0.z; un[3] += c[j]*p0.w;
                un[4] += c[j]*p1.x; un[5] += c[j]*p1.y; un[6] += c[j]*p1.z; un[7] += c[j]*p1.w;
            }
#pragma unroll
            for (int k = 0; k < 8; ++k) {
                float x   = un[k] - bmax[m];
                float rvp = fmaxf(x, 0.f);        // relu(Ax - bmax)
                float spn = rvp - x;              // relu(bmax - Ax)  (new s+)
                float y   = un[k] - bmin[m];
                float smn = fmaxf(y, 0.f);        // relu(Ax - bmin)  (new s-)
                float rvm = smn - y;              // relu(bmin - Ax)
                res2 += rvp * rvp;
                res2 += rvm * rvm;
                h[k] = rvp - rvm;
                float xo  = uo[m][k] - bmax[m];
                float spo = fmaxf(-xo, 0.f);      // old s+
                float yo  = uo[m][k] - bmin[m];
                float smo = fmaxf(yo, 0.f);       // old s-
                float e1 = spn - spo;
                float e2 = smn - smo;
                ds2 += e1 * e1;
                ds2 += e2 * e2;
                uo[m][k] = un[k];
            }
#pragma unroll
            for (int j = 0; j < 16; ++j) {
                float4 p0 = *(const float4*)&Pt[m][j][4*l];
                float4 p1 = *(const float4*)&Pt[m][j][64 + 4*l];
                pjp[j] += h[0]*p0.x + h[1]*p0.y + h[2]*p0.z + h[3]*p0.w
                        + h[4]*p1.x + h[5]*p1.y + h[6]*p1.z + h[7]*p1.w;
            }
        }

        bfly16(pjp, res2, ds2);
#pragma unroll
        for (int j = 0; j < 16; ++j) pj[j] = pjp[j];

        // cq for next iteration: AtA * c (distributed matvec + broadcast)
        float cqd = 0.f;
#pragma unroll
        for (int k = 0; k < 16; ++k) cqd += ata[l][k] * c[k];
#pragma unroll
        for (int k = 0; k < 16; ++k) cq[k] = __shfl(cqd, k, 16);

        // lambda update + norms
        float ln2 = 0.f;
#pragma unroll
        for (int k = 0; k < 16; ++k) { ln2 += pj[k] * pj[k]; L[k] -= pj[k]; }

        if (l == 0) {
            res_st[t][g] = sqrtf(res2);
            fix_st[t][g] = sqrtf(ln2) + sqrtf(ds2) + sqrtf(cdel2);
        }
    }

    // ---- outputs ----
    out[ch * (BATCH * NVARS) + row * 16 + l] = c_dist;   // lane l holds c[l]

    __syncthreads();
    const int t2 = threadIdx.x;
    if (t2 < 60) {
        int it = t2 % 15, r2 = t2 / 15, gb = r2 * 3;
        out[OUT_PST + it * BATCH + blockIdx.x * 4 + r2] =
            res_st[it][gb] + res_st[it][gb + 1] + res_st[it][gb + 2];
    } else if (t2 < 120) {
        int t3 = t2 - 60;
        int it = t3 % 15, r2 = t3 / 15, gb = r2 * 3;
        out[OUT_FST + it * BATCH + blockIdx.x * 4 + r2] =
            fix_st[it][gb] + fix_st[it][gb + 1] + fix_st[it][gb + 2];
    } else if (t2 < 124) {
        int r2 = t2 - 120, gb = r2 * 3;
        float s = 0.f;
        for (int it = 0; it < ITERS; ++it)
            s += fix_st[it][gb] + fix_st[it][gb + 1] + fix_st[it][gb + 2];
        out[OUT_ACCF + blockIdx.x * 4 + r2] = s * (1.f / 15.f);
    } else if (t2 < 128) {
        int r2 = t2 - 124, gb = r2 * 3;
        float s = 0.f;
        for (int it = 0; it < ITERS; ++it)
            s += res_st[it][gb] + res_st[it][gb + 1] + res_st[it][gb + 2];
        out[OUT_ACCP + blockIdx.x * 4 + r2] = s * (1.f / 15.f);
    }
}

extern "C" void kernel_launch(void* const* d_in, const int* in_sizes, int n_in,
                              void* d_out, int out_size, void* d_ws, size_t ws_size,
                              hipStream_t stream)
{
    const float* P    = (const float*)d_in[0];
    const float* Pdm  = (const float*)d_in[1];
    const float* Pddm = (const float*)d_in[2];
    const float* lamv = (const float*)d_in[3];
    const float* lamp = (const float*)d_in[4];
    const float* lamr = (const float*)d_in[5];
    const float* cinv = (const float*)d_in[6];
    const float* cinp = (const float*)d_in[7];
    const float* cinr = (const float*)d_in[8];
    const float* beqv = (const float*)d_in[9];
    const float* beqp = (const float*)d_in[10];
    const float* beqr = (const float*)d_in[11];
    const float* c0v  = (const float*)d_in[12];
    const float* c0p  = (const float*)d_in[13];
    const float* c0r  = (const float*)d_in[14];
    float* ws = (float*)d_ws;

    prep_kernel<<<1, 648, 0, stream>>>(P, Pdm, Pddm, ws);
    solve_kernel<<<2048, 192, 0, stream>>>(P, Pdm, Pddm,
        lamv, lamp, lamr, cinv, cinp, cinr,
        beqv, beqp, beqr, c0v, c0p, c0r,
        (float*)d_out, ws);
}